// Round 14
// baseline (384.898 us; speedup 1.0000x reference)
//
#include <hip/hip_runtime.h>
#include <math.h>

// Problem constants (fixed by setup_inputs)
#define BB 64
#define CC 512
#define CR 32
#define HW 3136
#define HW4 784                     // HW/4 float4 per plane
#define NBLK 1024                   // 4 blocks/CU x 256 CU: ALL co-resident
#define BPB 128                     // blocks per batch (512 planes / 4 per block)
#define BATCH_PAR (NBLK / BPB)      // 8 batches in flight per round
#define ROUNDS (BB / BATCH_PAR)     // 8
#define POISON 0xFFFFFFFFu          // s[] init pattern (NaN); finite means never collide
#define SPIN_MAX (1 << 22)          // liveness bound before scalar fallback

typedef float f32x4 __attribute__((ext_vector_type(4)));

// ---------------------------------------------------------------------------
// Single persistent dispatch, one HBM read of x total.
// R13 retry with the spill killed: amdgpu_waves_per_eu(4,4) pins exactly 4
// waves/SIMD -> 128-VGPR budget -> v[12]+vt (52 regs) stays in registers.
// (R13's launch_bounds(256,4) only set the MINIMUM; LLVM targeted 8 waves/EU
// -> 64 VGPRs -> full scratch spill, 132 MB extra traffic at 2.5 TB/s.)
// Sync: s[] words double as flags (poison-init, relaxed agent-scope ops,
// no fences -> no L2-writeback storms [R2 lesson]). Wait-free producers;
// bounded spin + scalar-pool fallback makes consumers livelock-free even
// without co-residency (insurance, never taken at 4 blocks/CU).
// ---------------------------------------------------------------------------
__global__ __launch_bounds__(256)
__attribute__((amdgpu_waves_per_eu(4, 4)))
void se_onepass(
    const float* __restrict__ x,
    const float* __restrict__ w1, const float* __restrict__ b1,
    const float* __restrict__ w2, const float* __restrict__ b2,
    float* __restrict__ out, unsigned int* __restrict__ s)
{
    const int t    = threadIdx.x;
    const int wave = t >> 6;
    const int lane = t & 63;
    __shared__ float s_sh[CC];
    __shared__ float h_sh[CR];

    for (int r = 0; r < ROUNDS; ++r) {
        const int batch = r * BATCH_PAR + (int)blockIdx.x / BPB;
        const int jblk  = (int)blockIdx.x % BPB;
        const int c     = jblk * 4 + wave;        // this wave's channel
        const int p     = batch * CC + c;         // this wave's plane

        // ---- pool: whole plane into registers (one vmcnt wait point) ----
        const f32x4* x4 = reinterpret_cast<const f32x4*>(x) + (size_t)p * HW4;
        f32x4 v[12];
        #pragma unroll
        for (int k = 0; k < 12; ++k)
            v[k] = x4[lane + 64 * k];
        f32x4 vt = (f32x4){0.f, 0.f, 0.f, 0.f};
        const bool tail = (lane < 16);            // 784 = 12*64 + 16
        if (tail) vt = x4[768 + lane];

        f32x4 a = vt;
        #pragma unroll
        for (int k = 0; k < 6; ++k) a += (v[k] + v[k + 6]);
        float acc = (a.x + a.y) + (a.z + a.w);
        #pragma unroll
        for (int off = 32; off > 0; off >>= 1)
            acc += __shfl_down(acc, off, 64);
        if (lane == 0) {
            const float m = acc * (1.0f / (float)HW);
            __hip_atomic_store(&s[p], __float_as_uint(m),
                               __ATOMIC_RELAXED, __HIP_MEMORY_SCOPE_AGENT);
        }

        // ---- gather s row: all 256 threads spin on 2 words each ----
        __syncthreads();                          // prev-round h_sh reads done
        #pragma unroll
        for (int j = 0; j < 2; ++j) {
            const int idx = t + j * 256;          // channel within batch
            unsigned int u;
            int spins = 0;
            for (;;) {
                u = __hip_atomic_load(&s[batch * CC + idx],
                                      __ATOMIC_RELAXED, __HIP_MEMORY_SCOPE_AGENT);
                if (u != POISON) break;
                if (++spins > SPIN_MAX) break;
                __builtin_amdgcn_s_sleep(2);
            }
            if (u != POISON) {
                s_sh[idx] = __uint_as_float(u);
            } else {
                // liveness fallback (never taken with full co-residency):
                // scalar-pool the plane directly from x.
                const float* xp = x + (size_t)(batch * CC + idx) * HW;
                float ssum = 0.0f;
                for (int q = 0; q < HW; ++q) ssum += xp[q];
                s_sh[idx] = ssum * (1.0f / (float)HW);
            }
        }
        __syncthreads();                          // s_sh ready

        // ---- fc: h = relu(s @ w1^T + b1), 8 threads per row ----
        {
            const int row = t >> 3, part = t & 7;
            const float* wr = w1 + row * CC;
            float ha = 0.0f;
            #pragma unroll
            for (int k = 0; k < CC / 8; ++k) {
                const int cc2 = part + 8 * k;
                ha = fmaf(s_sh[cc2], wr[cc2], ha);
            }
            ha += __shfl_down(ha, 4, 8);
            ha += __shfl_down(ha, 2, 8);
            ha += __shfl_down(ha, 1, 8);
            if (part == 0) h_sh[row] = fmaxf(ha + b1[row], 0.0f);
        }
        __syncthreads();                          // h_sh ready

        // ---- gate (redundant 32-FMA dot per thread) + scale + NT store ----
        float a2 = b2[c];
        const float* w2r = w2 + c * CR;
        #pragma unroll
        for (int rr = 0; rr < CR; ++rr)
            a2 = fmaf(h_sh[rr], w2r[rr], a2);
        const float gv = 1.0f / (1.0f + expf(-a2));

        f32x4* o4 = reinterpret_cast<f32x4*>(out) + (size_t)p * HW4;
        #pragma unroll
        for (int k = 0; k < 12; ++k)
            __builtin_nontemporal_store(v[k] * gv, &o4[lane + 64 * k]);
        if (tail) __builtin_nontemporal_store(vt * gv, &o4[768 + lane]);
    }
}

// ---------------------------------------------------------------------------
extern "C" void kernel_launch(void* const* d_in, const int* in_sizes, int n_in,
                              void* d_out, int out_size, void* d_ws, size_t ws_size,
                              hipStream_t stream) {
    const float* x  = (const float*)d_in[0];
    const float* w1 = (const float*)d_in[1];
    const float* b1 = (const float*)d_in[2];
    const float* w2 = (const float*)d_in[3];
    const float* b2 = (const float*)d_in[4];
    float* out = (float*)d_out;

    unsigned int* s = (unsigned int*)d_ws;        // [BB*CC] poison-init words

    // s must be poison at every call (replays don't re-poison ws)
    hipMemsetAsync(s, 0xFF, BB * CC * sizeof(unsigned int), stream);

    se_onepass<<<NBLK, 256, 0, stream>>>(x, w1, b1, w2, b2, out, s);
}

// Round 15
// 324.361 us; speedup vs baseline: 1.1866x; 1.1866x over previous
//
#include <hip/hip_runtime.h>
#include <math.h>

// Problem constants (fixed by setup_inputs)
#define BB 64
#define CC 512
#define CR 32
#define HW 3136
#define HW4 784                     // HW/4 float4 per plane
#define NBLK 1024                   // 4+ blocks/CU co-resident (R13-proven)
#define ROUNDS 16                   // 1024 blocks x 2 planes x 16 = 32768 planes
#define POISON 0xFFFFFFFFu          // s[] init pattern (NaN); real means never collide

typedef float f32x4 __attribute__((ext_vector_type(4)));

// ---------------------------------------------------------------------------
// Single persistent dispatch; x crosses the fabric exactly once.
// R13/R14 retried with the spill fixed GEOMETRICALLY: one plane per BLOCK
// (256 threads) -> 13 VGPR/thread/plane instead of 52 (wave-per-plane).
// 2 planes per block per round = ~32 data VGPRs: fits ANY allocation >= 64,
// so register residency across the sync can't spill by construction.
// Sync: poison-init s[] words double as flags; relaxed agent-scope ops only
// (no fences -> no L2 writeback storms). Every block redundantly computes
// the tiny fc from its batch's s row (one L3 round-trip, R13-proven).
// ---------------------------------------------------------------------------
__global__ __launch_bounds__(256) void se_onepass(
    const float* __restrict__ x,
    const float* __restrict__ w1, const float* __restrict__ b1,
    const float* __restrict__ w2, const float* __restrict__ b2,
    float* __restrict__ out, unsigned int* __restrict__ s)
{
    const int t    = threadIdx.x;
    const int wv   = t >> 6;
    const int lane = t & 63;
    __shared__ float s_sh[CC];
    __shared__ float h_sh[CR];
    __shared__ float red[8];                      // 4 waves x 2 planes

    for (int r = 0; r < ROUNDS; ++r) {
        const int pA    = r * (2 * NBLK) + 2 * (int)blockIdx.x;
        const int pB    = pA + 1;
        const int batch = pA >> 9;                // CC == 512; both planes same batch
        const int cA    = pA & (CC - 1);
        const int cB    = cA + 1;

        // ---- pool: both planes into registers (NT loads: x is read once,
        //      don't pollute L2/L3). 3 f32x4 + tail per thread per plane. ----
        const f32x4* xA = reinterpret_cast<const f32x4*>(x) + (size_t)pA * HW4;
        const f32x4* xB = reinterpret_cast<const f32x4*>(x) + (size_t)pB * HW4;
        f32x4 vA[3], vB[3];
        #pragma unroll
        for (int k = 0; k < 3; ++k)
            vA[k] = __builtin_nontemporal_load(&xA[t + 256 * k]);
        #pragma unroll
        for (int k = 0; k < 3; ++k)
            vB[k] = __builtin_nontemporal_load(&xB[t + 256 * k]);
        f32x4 vtA = (f32x4){0.f,0.f,0.f,0.f}, vtB = (f32x4){0.f,0.f,0.f,0.f};
        const bool tl = (t < 16);                 // tail: 784 = 3*256 + 16
        if (tl) {
            vtA = __builtin_nontemporal_load(&xA[768 + t]);
            vtB = __builtin_nontemporal_load(&xB[768 + t]);
        }

        f32x4 aA = (vA[0] + vA[1]) + (vA[2] + vtA);
        f32x4 aB = (vB[0] + vB[1]) + (vB[2] + vtB);
        float sA = (aA.x + aA.y) + (aA.z + aA.w);
        float sB = (aB.x + aB.y) + (aB.z + aB.w);
        #pragma unroll
        for (int off = 32; off > 0; off >>= 1) {
            sA += __shfl_down(sA, off, 64);
            sB += __shfl_down(sB, off, 64);
        }
        if (lane == 0) { red[wv] = sA; red[wv + 4] = sB; }
        __syncthreads();
        if (t == 0) {
            const float mA = ((red[0] + red[1]) + (red[2] + red[3])) * (1.0f / (float)HW);
            const float mB = ((red[4] + red[5]) + (red[6] + red[7])) * (1.0f / (float)HW);
            __hip_atomic_store(&s[pA], __float_as_uint(mA),
                               __ATOMIC_RELAXED, __HIP_MEMORY_SCOPE_AGENT);
            __hip_atomic_store(&s[pB], __float_as_uint(mB),
                               __ATOMIC_RELAXED, __HIP_MEMORY_SCOPE_AGENT);
        }

        // ---- gather batch's s row: 2 poison-polled words per thread ----
        #pragma unroll
        for (int j = 0; j < 2; ++j) {
            const int idx = t + j * 256;
            unsigned int u;
            do {
                u = __hip_atomic_load(&s[batch * CC + idx],
                                      __ATOMIC_RELAXED, __HIP_MEMORY_SCOPE_AGENT);
            } while (u == POISON);
            s_sh[idx] = __uint_as_float(u);
        }
        __syncthreads();                          // s_sh ready

        // ---- fc: h = relu(s @ w1^T + b1), 8 threads per row ----
        {
            const int row = t >> 3, part = t & 7;
            const float* wr = w1 + row * CC;
            float ha = 0.0f;
            #pragma unroll
            for (int k = 0; k < CC / 8; ++k) {
                const int cc2 = part + 8 * k;
                ha = fmaf(s_sh[cc2], wr[cc2], ha);
            }
            ha += __shfl_down(ha, 4, 8);
            ha += __shfl_down(ha, 2, 8);
            ha += __shfl_down(ha, 1, 8);
            if (part == 0) h_sh[row] = fmaxf(ha + b1[row], 0.0f);
        }
        __syncthreads();                          // h_sh ready

        // ---- gates (block-uniform c -> scalar w2 loads), scale, NT store ----
        float gA = b2[cA], gB = b2[cB];
        #pragma unroll
        for (int rr = 0; rr < CR; ++rr) {
            gA = fmaf(h_sh[rr], w2[cA * CR + rr], gA);
            gB = fmaf(h_sh[rr], w2[cB * CR + rr], gB);
        }
        gA = 1.0f / (1.0f + expf(-gA));
        gB = 1.0f / (1.0f + expf(-gB));

        f32x4* oA = reinterpret_cast<f32x4*>(out) + (size_t)pA * HW4;
        f32x4* oB = reinterpret_cast<f32x4*>(out) + (size_t)pB * HW4;
        #pragma unroll
        for (int k = 0; k < 3; ++k)
            __builtin_nontemporal_store(vA[k] * gA, &oA[t + 256 * k]);
        #pragma unroll
        for (int k = 0; k < 3; ++k)
            __builtin_nontemporal_store(vB[k] * gB, &oB[t + 256 * k]);
        if (tl) {
            __builtin_nontemporal_store(vtA * gA, &oA[768 + t]);
            __builtin_nontemporal_store(vtB * gB, &oB[768 + t]);
        }
        // No end-of-round barrier needed: next round's red/s_sh/h_sh writes
        // are ordered behind this round's reads by the three barriers above.
    }
}

// ---------------------------------------------------------------------------
extern "C" void kernel_launch(void* const* d_in, const int* in_sizes, int n_in,
                              void* d_out, int out_size, void* d_ws, size_t ws_size,
                              hipStream_t stream) {
    const float* x  = (const float*)d_in[0];
    const float* w1 = (const float*)d_in[1];
    const float* b1 = (const float*)d_in[2];
    const float* w2 = (const float*)d_in[3];
    const float* b2 = (const float*)d_in[4];
    float* out = (float*)d_out;

    unsigned int* s = (unsigned int*)d_ws;        // [BB*CC] poison-init words

    // s must be poison at every call (replays don't re-poison ws)
    hipMemsetAsync(s, 0xFF, BB * CC * sizeof(unsigned int), stream);

    se_onepass<<<NBLK, 256, 0, stream>>>(x, w1, b1, w2, b2, out, s);
}